// Round 2
// baseline (48444.772 us; speedup 1.0000x reference)
//
#include <hip/hip_runtime.h>

#define B   32
#define L   64
#define DH  1024
#define G4  4096
#define EK  512
#define V   32000

typedef unsigned long long ull;

__device__ __forceinline__ float sigm(float x){ return 1.f/(1.f+expf(-x)); }
__device__ __forceinline__ unsigned mono(float f){
  unsigned u = __float_as_uint(f);
  return (u & 0x80000000u) ? ~u : (u | 0x80000000u);
}

// zero h, c, hT (32x1024 each). grid 128 x 256
__global__ __launch_bounds__(256) void init_kernel(float* h, float* c, float* hT){
  int i = blockIdx.x*256 + threadIdx.x;
  if (i < B*DH){ h[i]=0.f; c[i]=0.f; hT[i]=0.f; }
}

// encT[t][k][b] = enc_embed[x[b][t]][k]. grid (64 t, 64 kblk) x 256
__global__ __launch_bounds__(256) void embT_kernel(const int* __restrict__ x,
    const float* __restrict__ emb, float* __restrict__ encT){
  int t = blockIdx.x;
  int b = threadIdx.x & 31;
  int k = blockIdx.y*8 + (threadIdx.x>>5);
  int tok = x[b*L + t];
  encT[((size_t)t*EK + k)*B + b] = emb[(size_t)tok*EK + k];
}

// LSTM gates GEMM, K-split into 512-row chunks. Splits [0,krA) read srcA/wx
// (optional relu), the rest read srcB/wh. Partials -> gpart[kr][jg][b].
// grid (64 colblk of 64 cols, nsplit) x 256. Thread = 2 cols x 4 rows.
__global__ __launch_bounds__(256) void gates_kernel(
    const float* __restrict__ srcA, int krA, int relu_in,
    const float* __restrict__ srcB,
    const float* __restrict__ wx, const float* __restrict__ wh,
    float* __restrict__ gpart)
{
  int tid = threadIdx.x;
  int cp = tid & 31, rowq = tid >> 5;
  int j = blockIdx.x*64 + cp*2;
  int kr = blockIdx.y;
  const float* src; const float* W; int relu = relu_in;
  if (kr < krA){ src = srcA + (size_t)kr*512*B;        W = wx + (size_t)kr*512*G4; }
  else         { src = srcB + (size_t)(kr-krA)*512*B;  W = wh + (size_t)(kr-krA)*512*G4; relu = 0; }
  float a00=0,a01=0,a10=0,a11=0,a20=0,a21=0,a30=0,a31=0;
  #pragma unroll 8
  for (int kk=0; kk<512; ++kk){
    float4 act = *reinterpret_cast<const float4*>(&src[kk*B + rowq*4]);
    if (relu){
      act.x = fmaxf(act.x,0.f); act.y = fmaxf(act.y,0.f);
      act.z = fmaxf(act.z,0.f); act.w = fmaxf(act.w,0.f);
    }
    float2 w = *reinterpret_cast<const float2*>(&W[(size_t)kk*G4 + j]);
    a00 += act.x*w.x; a01 += act.x*w.y;
    a10 += act.y*w.x; a11 += act.y*w.y;
    a20 += act.z*w.x; a21 += act.z*w.y;
    a30 += act.w*w.x; a31 += act.w*w.y;
  }
  *reinterpret_cast<float4*>(&gpart[((size_t)kr*G4 + j  )*B + rowq*4]) = make_float4(a00,a10,a20,a30);
  *reinterpret_cast<float4*>(&gpart[((size_t)kr*G4 + j+1)*B + rowq*4]) = make_float4(a01,a11,a21,a31);
}

// Merge gate partials + bias, LSTM cell update. grid 128 x 256.
__global__ __launch_bounds__(256) void cell_kernel(
    const float* __restrict__ gpart, int nkr,
    const float* __restrict__ bias, float* __restrict__ c,
    float* __restrict__ hT_out, float* __restrict__ h_out,
    float* __restrict__ enc_outs, int t)
{
  int tid = threadIdx.x;
  int b = tid & 31;
  int j = blockIdx.x*8 + (tid>>5);
  float iv = bias[j], fv = bias[DH+j], gv = bias[2*DH+j], ov = bias[3*DH+j];
  for (int kr=0; kr<nkr; ++kr){
    const float* g = &gpart[(size_t)kr*G4*B];
    iv += g[((size_t)(0*DH+j))*B + b];
    fv += g[((size_t)(1*DH+j))*B + b];
    gv += g[((size_t)(2*DH+j))*B + b];
    ov += g[((size_t)(3*DH+j))*B + b];
  }
  float cn = sigm(fv)*c[b*DH+j] + sigm(iv)*tanhf(gv);
  c[b*DH+j] = cn;
  float hv = sigm(ov)*tanhf(cn);
  hT_out[j*B + b] = hv;
  if (h_out)    h_out[b*DH + j] = hv;
  if (enc_outs) enc_outs[((size_t)b*L + t)*DH + j] = hv;
}

// Per-step attention + greedy-token resolve. grid 32 (one per b) x 256.
// Reduces prev step's packed argmax partials, gathers embedding (-> eT),
// seeds inpT with comb bias, computes softmax scores and ctx (-> ctxT).
__global__ __launch_bounds__(256) void attn_kernel(
    int t, const ull* __restrict__ pmax,
    const float* __restrict__ dec_embed, const float* __restrict__ attn_w,
    const float* __restrict__ attn_b, const float* __restrict__ h_in,
    const float* __restrict__ enc_outs,
    float* __restrict__ eT, float* __restrict__ ctxT,
    float* __restrict__ inpT, const float* __restrict__ comb_b)
{
  __shared__ float e_s[DH], h_s[DH], sc_s[4][64], aw_s[64];
  __shared__ ull m_s[256];
  __shared__ int tok_sh;
  int b = blockIdx.x, tid = threadIdx.x;
  if (t > 0){
    m_s[tid] = (tid < 250) ? pmax[b*256 + tid] : 0ull;
    __syncthreads();
    for (int off=128; off; off>>=1){
      if (tid < off && m_s[tid+off] > m_s[tid]) m_s[tid] = m_s[tid+off];
      __syncthreads();
    }
    if (tid==0) tok_sh = (int)(~(unsigned)(m_s[0] & 0xffffffffull));
  } else {
    if (tid==0) tok_sh = 127;
  }
  __syncthreads();
  int tok = tok_sh;
  for (int i=0;i<4;++i){
    int k = i*256 + tid;
    float ev = dec_embed[(size_t)tok*DH + k];
    float hv = h_in[b*DH + k];
    e_s[k]=ev; h_s[k]=hv;
    eT[k*B + b] = ev;
    inpT[k*B + b] = comb_b[k];
  }
  __syncthreads();
  int l = tid & 63, ks = tid >> 6;
  float p = 0.f;
  for (int kk=0; kk<512; ++kk){
    int k = ks*512 + kk;
    float sv = (k < DH) ? e_s[k] : h_s[k-DH];
    p += sv * attn_w[(size_t)k*L + l];
  }
  sc_s[ks][l] = p;
  __syncthreads();
  if (tid < 64){
    float s = sc_s[0][l]+sc_s[1][l]+sc_s[2][l]+sc_s[3][l] + attn_b[l];
    float m = s;
    for (int off=32; off; off>>=1) m = fmaxf(m, __shfl_xor(m, off));
    float e = expf(s-m);
    float sum = e;
    for (int off=32; off; off>>=1) sum += __shfl_xor(sum, off);
    aw_s[l] = e/sum;
  }
  __syncthreads();
  float c0=0,c1=0,c2=0,c3=0;
  for (int ll=0; ll<64; ++ll){
    float a = aw_s[ll];
    const float* er = &enc_outs[((size_t)b*L + ll)*DH];
    c0 += a*er[tid]; c1 += a*er[256+tid]; c2 += a*er[512+tid]; c3 += a*er[768+tid];
  }
  ctxT[(      tid)*B + b] = c0;
  ctxT[(256 + tid)*B + b] = c1;
  ctxT[(512 + tid)*B + b] = c2;
  ctxT[(768 + tid)*B + b] = c3;
}

// Combine GEMM, K-split x4, atomic accumulate into bias-seeded inpT[j][b].
// grid (16 colblk of 64 cols, 4) x 256. Thread = 2 cols x 4 rows.
__global__ __launch_bounds__(256) void comb_kernel(
    const float* __restrict__ eT, const float* __restrict__ ctxT,
    const float* __restrict__ comb_w, float* __restrict__ inpT)
{
  int tid = threadIdx.x;
  int cp = tid & 31, rowq = tid >> 5;
  int j = blockIdx.x*64 + cp*2;
  int kr = blockIdx.y;
  const float* src = (kr < 2) ? (eT + (size_t)kr*512*B) : (ctxT + (size_t)(kr-2)*512*B);
  const float* W = comb_w + (size_t)kr*512*DH;
  float a00=0,a01=0,a10=0,a11=0,a20=0,a21=0,a30=0,a31=0;
  #pragma unroll 8
  for (int kk=0; kk<512; ++kk){
    float4 act = *reinterpret_cast<const float4*>(&src[kk*B + rowq*4]);
    float2 w = *reinterpret_cast<const float2*>(&W[(size_t)kk*DH + j]);
    a00 += act.x*w.x; a01 += act.x*w.y;
    a10 += act.y*w.x; a11 += act.y*w.y;
    a20 += act.z*w.x; a21 += act.z*w.y;
    a30 += act.w*w.x; a31 += act.w*w.y;
  }
  atomicAdd(&inpT[(size_t)(j  )*B + rowq*4+0], a00);
  atomicAdd(&inpT[(size_t)(j  )*B + rowq*4+1], a10);
  atomicAdd(&inpT[(size_t)(j  )*B + rowq*4+2], a20);
  atomicAdd(&inpT[(size_t)(j  )*B + rowq*4+3], a30);
  atomicAdd(&inpT[(size_t)(j+1)*B + rowq*4+0], a01);
  atomicAdd(&inpT[(size_t)(j+1)*B + rowq*4+1], a11);
  atomicAdd(&inpT[(size_t)(j+1)*B + rowq*4+2], a21);
  atomicAdd(&inpT[(size_t)(j+1)*B + rowq*4+3], a31);
}

// Output projection: raw logits -> d_out, per-block sumexp + packed argmax.
// grid 250 x 256. Thread = 4 cols x 4 rows; block = 128 cols x 32 rows.
__global__ __launch_bounds__(256) void outproj_kernel(
    int t, const float* __restrict__ hT, const float* __restrict__ out_w,
    const float* __restrict__ out_b, float* __restrict__ out,
    float* __restrict__ psum, ull* __restrict__ pmax)
{
  __shared__ float sred[B][33];
  __shared__ ull   mred[B][33];
  int tid = threadIdx.x;
  int colq = tid & 31, rowq = tid >> 5;
  int j0 = blockIdx.x*128 + colq*4;
  int r0 = rowq*4;
  float acc[4][4];
  #pragma unroll
  for (int r=0;r<4;++r){ acc[r][0]=0;acc[r][1]=0;acc[r][2]=0;acc[r][3]=0; }
  #pragma unroll 8
  for (int k=0;k<DH;++k){
    float4 act = *reinterpret_cast<const float4*>(&hT[k*B + r0]);
    float4 w   = *reinterpret_cast<const float4*>(&out_w[(size_t)k*V + j0]);
    acc[0][0]+=act.x*w.x; acc[0][1]+=act.x*w.y; acc[0][2]+=act.x*w.z; acc[0][3]+=act.x*w.w;
    acc[1][0]+=act.y*w.x; acc[1][1]+=act.y*w.y; acc[1][2]+=act.y*w.z; acc[1][3]+=act.y*w.w;
    acc[2][0]+=act.z*w.x; acc[2][1]+=act.z*w.y; acc[2][2]+=act.z*w.z; acc[2][3]+=act.z*w.w;
    acc[3][0]+=act.w*w.x; acc[3][1]+=act.w*w.y; acc[3][2]+=act.w*w.z; acc[3][3]+=act.w*w.w;
  }
  float4 bj = *reinterpret_cast<const float4*>(&out_b[j0]);
  #pragma unroll
  for (int r=0;r<4;++r){
    float l0=acc[r][0]+bj.x, l1=acc[r][1]+bj.y, l2=acc[r][2]+bj.z, l3=acc[r][3]+bj.w;
    *reinterpret_cast<float4*>(&out[((size_t)(r0+r)*L + t)*V + j0]) = make_float4(l0,l1,l2,l3);
    float se = expf(l0)+expf(l1)+expf(l2)+expf(l3);
    ull m0 = ((ull)mono(l0)<<32) | (unsigned)(~(unsigned)(j0  ));
    ull m1 = ((ull)mono(l1)<<32) | (unsigned)(~(unsigned)(j0+1));
    ull m2 = ((ull)mono(l2)<<32) | (unsigned)(~(unsigned)(j0+2));
    ull m3 = ((ull)mono(l3)<<32) | (unsigned)(~(unsigned)(j0+3));
    if (m1>m0) m0=m1; if (m3>m2) m2=m3; if (m2>m0) m0=m2;
    sred[r0+r][colq] = se;
    mred[r0+r][colq] = m0;
  }
  __syncthreads();
  if (tid < B){
    float s=0.f; ull mx=0ull;
    for (int cc=0;cc<32;++cc){
      s += sred[tid][cc];
      if (mred[tid][cc] > mx) mx = mred[tid][cc];
    }
    psum[((size_t)t*B + tid)*256 + blockIdx.x] = s;
    pmax[tid*256 + blockIdx.x] = mx;
  }
}

// Final normalization: logp = logit - log(sumexp). grid (64 t, 32 b) x 256.
__global__ __launch_bounds__(256) void norm_kernel(
    float* __restrict__ out, const float* __restrict__ psum)
{
  __shared__ float ss[256];
  int t = blockIdx.x, b = blockIdx.y, tid = threadIdx.x;
  ss[tid] = (tid < 250) ? psum[((size_t)t*B + b)*256 + tid] : 0.f;
  __syncthreads();
  for (int off=128; off; off>>=1){
    if (tid < off) ss[tid] += ss[tid+off];
    __syncthreads();
  }
  float lse = logf(ss[0]);
  size_t base = ((size_t)b*L + t)*V;
  for (int i=tid; i<V; i+=256) out[base+i] -= lse;
}

extern "C" void kernel_launch(void* const* d_in, const int* in_sizes, int n_in,
                              void* d_out, int out_size, void* d_ws, size_t ws_size,
                              hipStream_t stream)
{
  const int*   x         = (const int*)  d_in[0];
  const float* enc_embed = (const float*)d_in[1];
  const float* enc_wx    = (const float*)d_in[2];
  const float* enc_wh    = (const float*)d_in[3];
  const float* enc_b     = (const float*)d_in[4];
  const float* dec_embed = (const float*)d_in[5];
  const float* attn_w    = (const float*)d_in[6];
  const float* attn_b    = (const float*)d_in[7];
  const float* comb_w    = (const float*)d_in[8];
  const float* comb_b    = (const float*)d_in[9];
  const float* dec_wx    = (const float*)d_in[10];
  const float* dec_wh    = (const float*)d_in[11];
  const float* dec_b     = (const float*)d_in[12];
  const float* out_w     = (const float*)d_in[13];
  const float* out_b     = (const float*)d_in[14];
  float* out = (float*)d_out;

  float* p = (float*)d_ws;
  float* enc_outs = p;            p += (size_t)B*L*DH;   // 2,097,152
  float* encT     = p;            p += (size_t)L*EK*B;   // 1,048,576
  float* gpart    = p;            p += (size_t)4*G4*B;   //   524,288
  float* psum     = p;            p += (size_t)L*B*256;  //   524,288
  float* hT0      = p;            p += B*DH;
  float* hT1      = p;            p += B*DH;
  float* h0d      = p;            p += B*DH;
  float* h1d      = p;            p += B*DH;
  float* c        = p;            p += B*DH;
  float* eT       = p;            p += B*DH;
  float* ctxT     = p;            p += B*DH;
  float* inpT     = p;            p += B*DH;
  ull*   pmax     = (ull*)p;                              // 8192 ull

  init_kernel<<<128,256,0,stream>>>(h0d, c, hT0);
  embT_kernel<<<dim3(L,64),256,0,stream>>>(x, enc_embed, encT);
  for (int t=0; t<L; ++t){
    const float* hTi = (t&1) ? hT1 : hT0;
    float*       hTo = (t&1) ? hT0 : hT1;
    gates_kernel<<<dim3(64,3),256,0,stream>>>(encT + (size_t)t*EK*B, 1, 0,
        hTi, enc_wx, enc_wh, gpart);
    cell_kernel<<<128,256,0,stream>>>(gpart, 3, enc_b, c, hTo, nullptr, enc_outs, t);
  }
  init_kernel<<<128,256,0,stream>>>(h0d, c, hT0);
  for (int t=0; t<L; ++t){
    const float* hTi = (t&1) ? hT1 : hT0;
    float*       hTo = (t&1) ? hT0 : hT1;
    const float* hi  = (t&1) ? h1d : h0d;
    float*       ho  = (t&1) ? h0d : h1d;
    attn_kernel<<<B,256,0,stream>>>(t, pmax, dec_embed, attn_w, attn_b,
        hi, enc_outs, eT, ctxT, inpT, comb_b);
    comb_kernel<<<dim3(16,4),256,0,stream>>>(eT, ctxT, comb_w, inpT);
    gates_kernel<<<dim3(64,4),256,0,stream>>>(inpT, 2, 1, hTi, dec_wx, dec_wh, gpart);
    cell_kernel<<<128,256,0,stream>>>(gpart, 4, dec_b, c, hTo, ho, nullptr, t);
    outproj_kernel<<<250,256,0,stream>>>(t, hTo, out_w, out_b, out, psum, pmax);
  }
  norm_kernel<<<dim3(L,B),256,0,stream>>>(out, psum);
}